// Round 3
// baseline (268.042 us; speedup 1.0000x reference)
//
#include <hip/hip_runtime.h>

// Problem constants (B,C,H,W)=(32,64,64,64), code_size=512
#define HWDIM 4096
#define CDIM  64
#define KDIM  512
#define ST_ELEMS   8388608   // 32*64*64*64
#define LOSS_OFF   8519680   // ST_ELEMS + 32*64*64

#define REP64(M) M(0) M(1) M(2) M(3) M(4) M(5) M(6) M(7) M(8) M(9) \
  M(10) M(11) M(12) M(13) M(14) M(15) M(16) M(17) M(18) M(19) \
  M(20) M(21) M(22) M(23) M(24) M(25) M(26) M(27) M(28) M(29) \
  M(30) M(31) M(32) M(33) M(34) M(35) M(36) M(37) M(38) M(39) \
  M(40) M(41) M(42) M(43) M(44) M(45) M(46) M(47) M(48) M(49) \
  M(50) M(51) M(52) M(53) M(54) M(55) M(56) M(57) M(58) M(59) \
  M(60) M(61) M(62) M(63)

// numpy fp32 pairwise sum-of-squares of 64 contiguous values (AVX-512 npyv
// emulation), array version — used for the codebook rows (validated R1/R2).
__device__ __forceinline__ float np_sumsq64(const float a[64]) {
#pragma clang fp contract(off)
  float v[16];
#pragma unroll
  for (int i = 0; i < 16; ++i) {
    float s0 = a[i]      * a[i];
    float s1 = a[i + 16] * a[i + 16];
    float s2 = a[i + 32] * a[i + 32];
    float s3 = a[i + 48] * a[i + 48];
    v[i] = (s0 + s1) + (s2 + s3);
  }
  float t0 = (v[0] + v[8])  + (v[4] + v[12]);
  float t1 = (v[1] + v[9])  + (v[5] + v[13]);
  float t2 = (v[2] + v[10]) + (v[6] + v[14]);
  float t3 = (v[3] + v[11]) + (v[7] + v[15]);
  return (t0 + t2) + (t1 + t3);
}

__global__ __launch_bounds__(256, 2) void vq_kernel(
    const float* __restrict__ x, const float* __restrict__ cb,
    float* __restrict__ st, float* __restrict__ idxo, float* __restrict__ loss)
{
  __shared__ float sc[KDIM];
  __shared__ float lred[4];

  const int tid = threadIdx.x;
  const int b   = blockIdx.x & 31;                 // batch index
  const int p   = ((blockIdx.x >> 5) << 8) + tid;  // pixel index 0..4095

  // Per-block codebook sum-of-squares (identical fp32 bits in every block).
  for (int k = tid; k < KDIM; k += 256) {
    float row[64];
#pragma unroll
    for (int c = 0; c < 64; ++c) row[c] = cb[(k << 6) + c];
    sc[k] = np_sumsq64(row);
  }

  // Load this thread's point into 64 named registers and PIN each with an
  // opaque asm. R2 evidence (VGPR_Count=48, VALUBusy 62%, dur 204us): the
  // compiler rematerialized these loads inside the k-loop (~4 GB of L1/L2
  // re-reads). "+v" makes the producer opaque -> must stay VGPR-resident.
  const float* xp = x + (size_t)b * (CDIM * HWDIM) + p;
#define XLOAD(i) float x##i = xp[(i) * HWDIM]; asm("" : "+v"(x##i));
  REP64(XLOAD)
#undef XLOAD

  // numpy pairwise sum-of-squares of x, named-register version (same tree).
  float S;
  {
#pragma clang fp contract(off)
#define SQ(i, j, k2, l) float v##i = ((x##i * x##i) + (x##j * x##j)) + ((x##k2 * x##k2) + (x##l * x##l));
    SQ(0,16,32,48) SQ(1,17,33,49) SQ(2,18,34,50) SQ(3,19,35,51)
    SQ(4,20,36,52) SQ(5,21,37,53) SQ(6,22,38,54) SQ(7,23,39,55)
    SQ(8,24,40,56) SQ(9,25,41,57) SQ(10,26,42,58) SQ(11,27,43,59)
    SQ(12,28,44,60) SQ(13,29,45,61) SQ(14,30,46,62) SQ(15,31,47,63)
#undef SQ
    float t0 = (v0 + v8)  + (v4 + v12);
    float t1 = (v1 + v9)  + (v5 + v13);
    float t2 = (v2 + v10) + (v6 + v14);
    float t3 = (v3 + v11) + (v7 + v15);
    S = (t0 + t2) + (t1 + t3);
  }
  __syncthreads();

  // Argmin over 512 codes. Per-k dist bits identical to R1/R2 (sequential
  // fused-FMA chain ascending c; (S - 2*dot) + sc[k]; ascending-k strict '<').
  // Unroll x4: four INDEPENDENT chains cover the ~4-cyc FMA dep latency.
  float bestd = __builtin_inff();
  int   besti = 0;
  for (int k = 0; k < KDIM; k += 4) {
    const float* r0 = cb + (k << 6);   // wave-uniform -> scalar loads
    const float* r1 = r0 + 64;
    const float* r2 = r0 + 128;
    const float* r3 = r0 + 192;
    float d0 = 0.f, d1 = 0.f, d2 = 0.f, d3 = 0.f;
#define DOT4(i) \
    d0 = __builtin_fmaf(x##i, r0[i], d0); \
    d1 = __builtin_fmaf(x##i, r1[i], d1); \
    d2 = __builtin_fmaf(x##i, r2[i], d2); \
    d3 = __builtin_fmaf(x##i, r3[i], d3);
    REP64(DOT4)
#undef DOT4
    float e0, e1, e2, e3;
    {
#pragma clang fp contract(off)
      e0 = (S - (d0 + d0)) + sc[k];
      e1 = (S - (d1 + d1)) + sc[k + 1];
      e2 = (S - (d2 + d2)) + sc[k + 2];
      e3 = (S - (d3 + d3)) + sc[k + 3];
    }
    if (e0 < bestd) { bestd = e0; besti = k; }
    if (e1 < bestd) { bestd = e1; besti = k + 1; }
    if (e2 < bestd) { bestd = e2; besti = k + 2; }
    if (e3 < bestd) { bestd = e3; besti = k + 3; }
  }

  // Gather chosen code row, write st (coalesced: lane = consecutive p),
  // accumulate loss partial (loose tolerance; order free).
  const float* crow = cb + (besti << 6);
  float* stp = st + (size_t)b * (CDIM * HWDIM) + p;
  float lsum = 0.f;
#define EPI(i) { float cv = crow[i]; float df; \
    { _Pragma("clang fp contract(off)") df = cv - x##i; } \
    lsum = __builtin_fmaf(df, df, lsum); stp[(i) * HWDIM] = cv; }
  REP64(EPI)
#undef EPI

  // indices[b, p] as float (d_out is one flat float32 buffer).
  idxo[b * HWDIM + p] = (float)besti;

  // Block reduce loss, one atomic per block. 1.25/(N*C) is exact pow2*5.
#pragma unroll
  for (int off = 32; off > 0; off >>= 1) lsum += __shfl_down(lsum, off);
  if ((tid & 63) == 0) lred[tid >> 6] = lsum;
  __syncthreads();
  if (tid == 0) {
    float t = (lred[0] + lred[1]) + (lred[2] + lred[3]);
    atomicAdd(loss, t * (1.25f / 8388608.f));
  }
}

extern "C" void kernel_launch(void* const* d_in, const int* in_sizes, int n_in,
                              void* d_out, int out_size, void* d_ws, size_t ws_size,
                              hipStream_t stream) {
  const float* x  = (const float*)d_in[0];   // (32,64,64,64) fp32
  const float* cb = (const float*)d_in[1];   // (512,64) fp32
  float* st   = (float*)d_out;               // (32,64,64,64)
  float* idxo = (float*)d_out + ST_ELEMS;    // (32,64,64) as float
  float* loss = (float*)d_out + LOSS_OFF;    // scalar

  hipMemsetAsync(loss, 0, sizeof(float), stream);  // d_out is poisoned each call
  vq_kernel<<<dim3(512), dim3(256), 0, stream>>>(x, cb, st, idxo, loss);
}

// Round 4
// 267.745 us; speedup vs baseline: 1.0011x; 1.0011x over previous
//
#include <hip/hip_runtime.h>

// Problem constants (B,C,H,W)=(32,64,64,64), code_size=512
#define HWDIM 4096
#define CDIM  64
#define KDIM  512
#define ST_ELEMS   8388608   // 32*64*64*64
#define LOSS_OFF   8519680   // ST_ELEMS + 32*64*64

#define REP64(M) M(0) M(1) M(2) M(3) M(4) M(5) M(6) M(7) M(8) M(9) \
  M(10) M(11) M(12) M(13) M(14) M(15) M(16) M(17) M(18) M(19) \
  M(20) M(21) M(22) M(23) M(24) M(25) M(26) M(27) M(28) M(29) \
  M(30) M(31) M(32) M(33) M(34) M(35) M(36) M(37) M(38) M(39) \
  M(40) M(41) M(42) M(43) M(44) M(45) M(46) M(47) M(48) M(49) \
  M(50) M(51) M(52) M(53) M(54) M(55) M(56) M(57) M(58) M(59) \
  M(60) M(61) M(62) M(63)

// numpy fp32 pairwise sum-of-squares of 64 contiguous values (AVX-512 npyv
// emulation), array version — used for the codebook rows (validated R1-R3).
__device__ __forceinline__ float np_sumsq64(const float a[64]) {
#pragma clang fp contract(off)
  float v[16];
#pragma unroll
  for (int i = 0; i < 16; ++i) {
    float s0 = a[i]      * a[i];
    float s1 = a[i + 16] * a[i + 16];
    float s2 = a[i + 32] * a[i + 32];
    float s3 = a[i + 48] * a[i + 48];
    v[i] = (s0 + s1) + (s2 + s3);
  }
  float t0 = (v[0] + v[8])  + (v[4] + v[12]);
  float t1 = (v[1] + v[9])  + (v[5] + v[13]);
  float t2 = (v[2] + v[10]) + (v[6] + v[14]);
  float t3 = (v[3] + v[11]) + (v[7] + v[15]);
  return (t0 + t2) + (t1 + t3);
}

// amdgpu_waves_per_eu(2,2): R1-R3 evidence (VGPR_Count 48-52 despite 64 live
// x-values, VALUBusy ~60%, dur ~3.75x the FMA floor) — with only a MIN waves
// bound the scheduler squeezes pressure toward 8 waves/EU (<=64 VGPR) and
// spills x to scratch inside the k-loop. Runtime occupancy is grid-limited to
// 2 waves/EU anyway (512 blocks / 256 CUs), so pin min=max=2 -> 256-VGPR
// budget -> x stays register-resident.
__global__ __launch_bounds__(256)
__attribute__((amdgpu_waves_per_eu(2, 2)))
void vq_kernel(
    const float* __restrict__ x, const float* __restrict__ cb,
    float* __restrict__ st, float* __restrict__ idxo, float* __restrict__ loss)
{
  __shared__ float sc[KDIM];
  __shared__ float lred[4];

  const int tid = threadIdx.x;
  const int b   = blockIdx.x & 31;                 // batch index
  const int p   = ((blockIdx.x >> 5) << 8) + tid;  // pixel index 0..4095

  // Per-block codebook sum-of-squares (identical fp32 bits in every block).
  for (int k = tid; k < KDIM; k += 256) {
    float row[64];
#pragma unroll
    for (int c = 0; c < 64; ++c) row[c] = cb[(k << 6) + c];
    sc[k] = np_sumsq64(row);
  }

  // Load this thread's point into 64 named registers (kept resident now that
  // the register budget allows it).
  const float* xp = x + (size_t)b * (CDIM * HWDIM) + p;
#define XLOAD(i) float x##i = xp[(i) * HWDIM]; asm("" : "+v"(x##i));
  REP64(XLOAD)
#undef XLOAD

  // numpy pairwise sum-of-squares of x, named-register version (same tree).
  float S;
  {
#pragma clang fp contract(off)
#define SQ(i, j, k2, l) float v##i = ((x##i * x##i) + (x##j * x##j)) + ((x##k2 * x##k2) + (x##l * x##l));
    SQ(0,16,32,48) SQ(1,17,33,49) SQ(2,18,34,50) SQ(3,19,35,51)
    SQ(4,20,36,52) SQ(5,21,37,53) SQ(6,22,38,54) SQ(7,23,39,55)
    SQ(8,24,40,56) SQ(9,25,41,57) SQ(10,26,42,58) SQ(11,27,43,59)
    SQ(12,28,44,60) SQ(13,29,45,61) SQ(14,30,46,62) SQ(15,31,47,63)
#undef SQ
    float t0 = (v0 + v8)  + (v4 + v12);
    float t1 = (v1 + v9)  + (v5 + v13);
    float t2 = (v2 + v10) + (v6 + v14);
    float t3 = (v3 + v11) + (v7 + v15);
    S = (t0 + t2) + (t1 + t3);
  }
  __syncthreads();

  // Argmin over 512 codes. Per-k dist bits identical to R1-R3 (sequential
  // fused-FMA chain ascending c; (S - 2*dot) + sc[k]; ascending-k strict '<').
  // Unroll x4: four INDEPENDENT chains cover the ~4-cyc FMA dep latency.
  float bestd = __builtin_inff();
  int   besti = 0;
  for (int k = 0; k < KDIM; k += 4) {
    const float* r0 = cb + (k << 6);   // wave-uniform -> scalar loads
    const float* r1 = r0 + 64;
    const float* r2 = r0 + 128;
    const float* r3 = r0 + 192;
    float d0 = 0.f, d1 = 0.f, d2 = 0.f, d3 = 0.f;
#define DOT4(i) \
    d0 = __builtin_fmaf(x##i, r0[i], d0); \
    d1 = __builtin_fmaf(x##i, r1[i], d1); \
    d2 = __builtin_fmaf(x##i, r2[i], d2); \
    d3 = __builtin_fmaf(x##i, r3[i], d3);
    REP64(DOT4)
#undef DOT4
    float e0, e1, e2, e3;
    {
#pragma clang fp contract(off)
      e0 = (S - (d0 + d0)) + sc[k];
      e1 = (S - (d1 + d1)) + sc[k + 1];
      e2 = (S - (d2 + d2)) + sc[k + 2];
      e3 = (S - (d3 + d3)) + sc[k + 3];
    }
    if (e0 < bestd) { bestd = e0; besti = k; }
    if (e1 < bestd) { bestd = e1; besti = k + 1; }
    if (e2 < bestd) { bestd = e2; besti = k + 2; }
    if (e3 < bestd) { bestd = e3; besti = k + 3; }
  }

  // Gather chosen code row, write st (coalesced: lane = consecutive p),
  // accumulate loss partial (loose tolerance; order free).
  const float* crow = cb + (besti << 6);
  float* stp = st + (size_t)b * (CDIM * HWDIM) + p;
  float lsum = 0.f;
#define EPI(i) { float cv = crow[i]; float df; \
    { _Pragma("clang fp contract(off)") df = cv - x##i; } \
    lsum = __builtin_fmaf(df, df, lsum); stp[(i) * HWDIM] = cv; }
  REP64(EPI)
#undef EPI

  // indices[b, p] as float (d_out is one flat float32 buffer).
  idxo[b * HWDIM + p] = (float)besti;

  // Block reduce loss, one atomic per block. 1.25/(N*C) is exact pow2*5.
#pragma unroll
  for (int off = 32; off > 0; off >>= 1) lsum += __shfl_down(lsum, off);
  if ((tid & 63) == 0) lred[tid >> 6] = lsum;
  __syncthreads();
  if (tid == 0) {
    float t = (lred[0] + lred[1]) + (lred[2] + lred[3]);
    atomicAdd(loss, t * (1.25f / 8388608.f));
  }
}

extern "C" void kernel_launch(void* const* d_in, const int* in_sizes, int n_in,
                              void* d_out, int out_size, void* d_ws, size_t ws_size,
                              hipStream_t stream) {
  const float* x  = (const float*)d_in[0];   // (32,64,64,64) fp32
  const float* cb = (const float*)d_in[1];   // (512,64) fp32
  float* st   = (float*)d_out;               // (32,64,64,64)
  float* idxo = (float*)d_out + ST_ELEMS;    // (32,64,64) as float
  float* loss = (float*)d_out + LOSS_OFF;    // scalar

  hipMemsetAsync(loss, 0, sizeof(float), stream);  // d_out is poisoned each call
  vq_kernel<<<dim3(512), dim3(256), 0, stream>>>(x, cb, st, idxo, loss);
}

// Round 5
// 258.706 us; speedup vs baseline: 1.0361x; 1.0349x over previous
//
#include <hip/hip_runtime.h>

// Problem constants (B,C,H,W)=(32,64,64,64), code_size=512
#define HWDIM 4096
#define CDIM  64
#define KDIM  512
#define ST_ELEMS   8388608   // 32*64*64*64
#define LOSS_OFF   8519680   // ST_ELEMS + 32*64*64

#define REP64(M) M(0) M(1) M(2) M(3) M(4) M(5) M(6) M(7) M(8) M(9) \
  M(10) M(11) M(12) M(13) M(14) M(15) M(16) M(17) M(18) M(19) \
  M(20) M(21) M(22) M(23) M(24) M(25) M(26) M(27) M(28) M(29) \
  M(30) M(31) M(32) M(33) M(34) M(35) M(36) M(37) M(38) M(39) \
  M(40) M(41) M(42) M(43) M(44) M(45) M(46) M(47) M(48) M(49) \
  M(50) M(51) M(52) M(53) M(54) M(55) M(56) M(57) M(58) M(59) \
  M(60) M(61) M(62) M(63)

// numpy fp32 pairwise sum-of-squares of 64 contiguous values (AVX-512 npyv
// emulation) — used for the codebook rows (bit-validated R1-R4).
__device__ __forceinline__ float np_sumsq64(const float a[64]) {
#pragma clang fp contract(off)
  float v[16];
#pragma unroll
  for (int i = 0; i < 16; ++i) {
    float s0 = a[i]      * a[i];
    float s1 = a[i + 16] * a[i + 16];
    float s2 = a[i + 32] * a[i + 32];
    float s3 = a[i + 48] * a[i + 48];
    v[i] = (s0 + s1) + (s2 + s3);
  }
  float t0 = (v[0] + v[8])  + (v[4] + v[12]);
  float t1 = (v[1] + v[9])  + (v[5] + v[13]);
  float t2 = (v[2] + v[10]) + (v[6] + v[14]);
  float t3 = (v[3] + v[11]) + (v[7] + v[15]);
  return (t0 + t2) + (t1 + t3);
}

// waves_per_eu(2,2): runtime occupancy is capped at 2 waves/EU anyway
// (512 blocks / 256 CU; 66KB LDS -> 2 blocks/CU). Pin it so the register
// allocator has the full 256-VGPR budget for x residency + ds staging.
__global__ __launch_bounds__(256)
__attribute__((amdgpu_waves_per_eu(2, 2)))
void vq_kernel(
    const float* __restrict__ x, const float* __restrict__ cb,
    float* __restrict__ st, float* __restrict__ idxo, float* __restrict__ loss)
{
  // Half-codebook LDS tile (256 rows x 64 floats = 64 KB) + sc + reduce pad.
  __shared__ __align__(16) float lcb[256 * 64];
  __shared__ float sc[KDIM];
  __shared__ float lred[4];

  const int tid  = threadIdx.x;
  const int wave = tid >> 6;
  const int b    = blockIdx.x & 31;                 // batch index
  const int p    = ((blockIdx.x >> 5) << 8) + tid;  // pixel index 0..4095

  // Per-block codebook sum-of-squares (identical fp32 bits in every block).
  for (int k = tid; k < KDIM; k += 256) {
    float row[64];
#pragma unroll
    for (int c = 0; c < 64; ++c) row[c] = cb[(k << 6) + c];
    sc[k] = np_sumsq64(row);
  }

  // Load this thread's point into 64 named, pinned registers.
  const float* xp = x + (size_t)b * (CDIM * HWDIM) + p;
#define XLOAD(i) float x##i = xp[(i) * HWDIM]; asm("" : "+v"(x##i));
  REP64(XLOAD)
#undef XLOAD

  // numpy pairwise sum-of-squares of x (same tree, named-register form).
  float S;
  {
#pragma clang fp contract(off)
#define SQ(i, j, k2, l) float v##i = ((x##i * x##i) + (x##j * x##j)) + ((x##k2 * x##k2) + (x##l * x##l));
    SQ(0,16,32,48) SQ(1,17,33,49) SQ(2,18,34,50) SQ(3,19,35,51)
    SQ(4,20,36,52) SQ(5,21,37,53) SQ(6,22,38,54) SQ(7,23,39,55)
    SQ(8,24,40,56) SQ(9,25,41,57) SQ(10,26,42,58) SQ(11,27,43,59)
    SQ(12,28,44,60) SQ(13,29,45,61) SQ(14,30,46,62) SQ(15,31,47,63)
#undef SQ
    float t0 = (v0 + v8)  + (v4 + v12);
    float t1 = (v1 + v9)  + (v5 + v13);
    float t2 = (v2 + v10) + (v6 + v14);
    float t3 = (v3 + v11) + (v7 + v15);
    S = (t0 + t2) + (t1 + t3);
  }
  __syncthreads();

  // Argmin over 512 codes in 2 passes of 256 LDS-staged rows.
  // R4 evidence: dur flat at 208us with x resident -> the k-loop is
  // latency-bound on per-lane global row loads (no s_load, shallow VMEM
  // staging at VGPR=88). LDS rows give broadcast ds_read_b128 with immediate
  // offsets + compiler fine-grained lgkmcnt pipelining (m97 pattern).
  // Numerics bit-identical to R1-R4: same fused-FMA chain order, same
  // (S - 2*dot) + sc[k], ascending-k strict '<'.
  float bestd = __builtin_inff();
  int   besti = 0;
  for (int pass = 0; pass < 2; ++pass) {
    // Stage 256 rows (64 KB): 16 iters x 256 lanes x 16 B, direct-to-LDS.
    // global_load_lds dest = wave-uniform base + lane*16; our layout is the
    // exact linear order the wave's lanes load -> contiguous, no padding.
    for (int i = 0; i < 16; ++i) {
      const int j = (i << 8) + tid;                       // float4 chunk id
      const float* g = cb + ((pass << 14) + (j << 2));    // pass*16384 floats
      float* l = lcb + ((i << 10) + (wave << 8));         // uniform per wave
      __builtin_amdgcn_global_load_lds(
          (const __attribute__((address_space(1))) void*)g,
          (__attribute__((address_space(3))) void*)l, 16, 0, 0);
    }
    __syncthreads();

    const int kbase = pass << 8;
    for (int kk = 0; kk < 256; kk += 4) {
      const float* r0 = lcb + (kk << 6);   // broadcast ds reads, imm offsets
      const float* r1 = r0 + 64;
      const float* r2 = r0 + 128;
      const float* r3 = r0 + 192;
      float d0 = 0.f, d1 = 0.f, d2 = 0.f, d3 = 0.f;
#define DOT4(i) \
      d0 = __builtin_fmaf(x##i, r0[i], d0); \
      d1 = __builtin_fmaf(x##i, r1[i], d1); \
      d2 = __builtin_fmaf(x##i, r2[i], d2); \
      d3 = __builtin_fmaf(x##i, r3[i], d3);
      REP64(DOT4)
#undef DOT4
      float e0, e1, e2, e3;
      {
#pragma clang fp contract(off)
        e0 = (S - (d0 + d0)) + sc[kbase + kk];
        e1 = (S - (d1 + d1)) + sc[kbase + kk + 1];
        e2 = (S - (d2 + d2)) + sc[kbase + kk + 2];
        e3 = (S - (d3 + d3)) + sc[kbase + kk + 3];
      }
      if (e0 < bestd) { bestd = e0; besti = kbase + kk; }
      if (e1 < bestd) { bestd = e1; besti = kbase + kk + 1; }
      if (e2 < bestd) { bestd = e2; besti = kbase + kk + 2; }
      if (e3 < bestd) { bestd = e3; besti = kbase + kk + 3; }
    }
    __syncthreads();   // lcb reused next pass
  }

  // Gather chosen code row from global, write st (coalesced), loss partial.
  const float* crow = cb + (besti << 6);
  float* stp = st + (size_t)b * (CDIM * HWDIM) + p;
  float lsum = 0.f;
#define EPI(i) { float cv = crow[i]; float df; \
    { _Pragma("clang fp contract(off)") df = cv - x##i; } \
    lsum = __builtin_fmaf(df, df, lsum); stp[(i) * HWDIM] = cv; }
  REP64(EPI)
#undef EPI

  // indices[b, p] as float (d_out is one flat float32 buffer).
  idxo[b * HWDIM + p] = (float)besti;

  // Block reduce loss, one atomic per block. 1.25/(N*C) is exact pow2*5.
#pragma unroll
  for (int off = 32; off > 0; off >>= 1) lsum += __shfl_down(lsum, off);
  if ((tid & 63) == 0) lred[tid >> 6] = lsum;
  __syncthreads();
  if (tid == 0) {
    float t = (lred[0] + lred[1]) + (lred[2] + lred[3]);
    atomicAdd(loss, t * (1.25f / 8388608.f));
  }
}

extern "C" void kernel_launch(void* const* d_in, const int* in_sizes, int n_in,
                              void* d_out, int out_size, void* d_ws, size_t ws_size,
                              hipStream_t stream) {
  const float* x  = (const float*)d_in[0];   // (32,64,64,64) fp32
  const float* cb = (const float*)d_in[1];   // (512,64) fp32
  float* st   = (float*)d_out;               // (32,64,64,64)
  float* idxo = (float*)d_out + ST_ELEMS;    // (32,64,64) as float
  float* loss = (float*)d_out + LOSS_OFF;    // scalar

  hipMemsetAsync(loss, 0, sizeof(float), stream);  // d_out is poisoned each call
  vq_kernel<<<dim3(512), dim3(256), 0, stream>>>(x, cb, st, idxo, loss);
}

// Round 6
// 250.968 us; speedup vs baseline: 1.0680x; 1.0308x over previous
//
#include <hip/hip_runtime.h>

// Problem constants (B,C,H,W)=(32,64,64,64), code_size=512
#define HWDIM 4096
#define CDIM  64
#define KDIM  512
#define ST_ELEMS   8388608   // 32*64*64*64
#define LOSS_OFF   8519680   // ST_ELEMS + 32*64*64

#define REP64(M) M(0) M(1) M(2) M(3) M(4) M(5) M(6) M(7) M(8) M(9) \
  M(10) M(11) M(12) M(13) M(14) M(15) M(16) M(17) M(18) M(19) \
  M(20) M(21) M(22) M(23) M(24) M(25) M(26) M(27) M(28) M(29) \
  M(30) M(31) M(32) M(33) M(34) M(35) M(36) M(37) M(38) M(39) \
  M(40) M(41) M(42) M(43) M(44) M(45) M(46) M(47) M(48) M(49) \
  M(50) M(51) M(52) M(53) M(54) M(55) M(56) M(57) M(58) M(59) \
  M(60) M(61) M(62) M(63)

// 16-float vector -> s_load_dwordx16 when loaded via constant address space.
typedef float vf16 __attribute__((ext_vector_type(16)));
typedef __attribute__((address_space(4))) const vf16 cvf16;

// numpy fp32 pairwise sum-of-squares of 64 contiguous values (AVX-512 npyv
// emulation) — bit-validated R1-R5.
__device__ __forceinline__ float np_sumsq64(const float a[64]) {
#pragma clang fp contract(off)
  float v[16];
#pragma unroll
  for (int i = 0; i < 16; ++i) {
    float s0 = a[i]      * a[i];
    float s1 = a[i + 16] * a[i + 16];
    float s2 = a[i + 32] * a[i + 32];
    float s3 = a[i + 48] * a[i + 48];
    v[i] = (s0 + s1) + (s2 + s3);
  }
  float t0 = (v[0] + v[8])  + (v[4] + v[12]);
  float t1 = (v[1] + v[9])  + (v[5] + v[13]);
  float t2 = (v[2] + v[10]) + (v[6] + v[14]);
  float t3 = (v[3] + v[11]) + (v[7] + v[15]);
  return (t0 + t2) + (t1 + t3);
}

// waves_per_eu(2,2): runtime occupancy is grid-limited to 2 waves/EU anyway;
// pinning gives the allocator the 256-VGPR budget so x stays resident (R4).
__global__ __launch_bounds__(256)
__attribute__((amdgpu_waves_per_eu(2, 2)))
void vq_kernel(
    const float* __restrict__ x, const float* __restrict__ cb,
    float* __restrict__ st, float* __restrict__ idxo, float* __restrict__ loss)
{
  __shared__ float sc[KDIM];
  __shared__ float lred[4];

  const int tid = threadIdx.x;
  const int b   = blockIdx.x & 31;                 // batch index
  const int p   = ((blockIdx.x >> 5) << 8) + tid;  // pixel index 0..4095

  // Constant-AS view of the codebook: wave-uniform row addresses -> the
  // backend emits s_load_dwordx16 (scalar pipe). R1-R5 evidence: rows via
  // vector loads (global OR LDS) all plateau at ~208us = broadcast
  // data-return bandwidth (64 lanes x 16B per b128 ~ 8cyc/CU); SGPR rows
  // remove that traffic entirely, leaving the 55us FMA-issue floor.
  cvf16* rows = (cvf16*)(uintptr_t)cb;   // row k = chunks [4k .. 4k+3]

  // Per-block codebook sum-of-squares (per-lane k -> divergent: vector loads).
  for (int k = tid; k < KDIM; k += 256) {
    float row[64];
#pragma unroll
    for (int c = 0; c < 64; ++c) row[c] = cb[(k << 6) + c];
    sc[k] = np_sumsq64(row);
  }

  // Load this thread's point into 64 named, pinned registers.
  const float* xp = x + (size_t)b * (CDIM * HWDIM) + p;
#define XLOAD(i) float x##i = xp[(i) * HWDIM]; asm("" : "+v"(x##i));
  REP64(XLOAD)
#undef XLOAD

  // numpy pairwise sum-of-squares of x (same tree, named-register form).
  float S;
  {
#pragma clang fp contract(off)
#define SQ(i, j, k2, l) float v##i = ((x##i * x##i) + (x##j * x##j)) + ((x##k2 * x##k2) + (x##l * x##l));
    SQ(0,16,32,48) SQ(1,17,33,49) SQ(2,18,34,50) SQ(3,19,35,51)
    SQ(4,20,36,52) SQ(5,21,37,53) SQ(6,22,38,54) SQ(7,23,39,55)
    SQ(8,24,40,56) SQ(9,25,41,57) SQ(10,26,42,58) SQ(11,27,43,59)
    SQ(12,28,44,60) SQ(13,29,45,61) SQ(14,30,46,62) SQ(15,31,47,63)
#undef SQ
    float t0 = (v0 + v8)  + (v4 + v12);
    float t1 = (v1 + v9)  + (v5 + v13);
    float t2 = (v2 + v10) + (v6 + v14);
    float t3 = (v3 + v11) + (v7 + v15);
    S = (t0 + t2) + (t1 + t3);
  }
  __syncthreads();

  // Argmin over 512 codes, 4 rows per iteration, rows streamed through
  // SGPRs in 16-float chunks. Per-chain FMA order is ascending c (chunk 0
  // elements 0..15, then 16..31, ...) — bit-identical to R1-R5.
  float bestd = __builtin_inff();
  int   besti = 0;

#define FF(T, XI) \
    d0 = __builtin_fmaf(x##XI, c0[T], d0); \
    d1 = __builtin_fmaf(x##XI, c1[T], d1); \
    d2 = __builtin_fmaf(x##XI, c2[T], d2); \
    d3 = __builtin_fmaf(x##XI, c3[T], d3);
#define CHUNK(J, A0,A1,A2,A3,A4,A5,A6,A7,A8,A9,A10,A11,A12,A13,A14,A15) \
  { vf16 c0 = rows[rb + (J)];      vf16 c1 = rows[rb + 4 + (J)];        \
    vf16 c2 = rows[rb + 8 + (J)];  vf16 c3 = rows[rb + 12 + (J)];       \
    FF(0,A0) FF(1,A1) FF(2,A2) FF(3,A3) FF(4,A4) FF(5,A5) FF(6,A6)      \
    FF(7,A7) FF(8,A8) FF(9,A9) FF(10,A10) FF(11,A11) FF(12,A12)         \
    FF(13,A13) FF(14,A14) FF(15,A15) }

  for (int k = 0; k < KDIM; k += 4) {
    const int rb = k << 2;            // x16-chunk index of row k
    float d0 = 0.f, d1 = 0.f, d2 = 0.f, d3 = 0.f;
    CHUNK(0,  0, 1, 2, 3, 4, 5, 6, 7, 8, 9,10,11,12,13,14,15)
    CHUNK(1, 16,17,18,19,20,21,22,23,24,25,26,27,28,29,30,31)
    CHUNK(2, 32,33,34,35,36,37,38,39,40,41,42,43,44,45,46,47)
    CHUNK(3, 48,49,50,51,52,53,54,55,56,57,58,59,60,61,62,63)
    float e0, e1, e2, e3;
    {
#pragma clang fp contract(off)
      e0 = (S - (d0 + d0)) + sc[k];
      e1 = (S - (d1 + d1)) + sc[k + 1];
      e2 = (S - (d2 + d2)) + sc[k + 2];
      e3 = (S - (d3 + d3)) + sc[k + 3];
    }
    if (e0 < bestd) { bestd = e0; besti = k; }
    if (e1 < bestd) { bestd = e1; besti = k + 1; }
    if (e2 < bestd) { bestd = e2; besti = k + 2; }
    if (e3 < bestd) { bestd = e3; besti = k + 3; }
  }
#undef CHUNK
#undef FF

  // Gather chosen code row (per-lane divergent -> vector loads), write st
  // (coalesced: lane = consecutive p), accumulate loss partial.
  const float* crow = cb + (besti << 6);
  float* stp = st + (size_t)b * (CDIM * HWDIM) + p;
  float lsum = 0.f;
#define EPI(i) { float cv = crow[i]; float df; \
    { _Pragma("clang fp contract(off)") df = cv - x##i; } \
    lsum = __builtin_fmaf(df, df, lsum); stp[(i) * HWDIM] = cv; }
  REP64(EPI)
#undef EPI

  // indices[b, p] as float (d_out is one flat float32 buffer).
  idxo[b * HWDIM + p] = (float)besti;

  // Block reduce loss, one atomic per block. 1.25/(N*C) is exact pow2*5.
#pragma unroll
  for (int off = 32; off > 0; off >>= 1) lsum += __shfl_down(lsum, off);
  if ((tid & 63) == 0) lred[tid >> 6] = lsum;
  __syncthreads();
  if (tid == 0) {
    float t = (lred[0] + lred[1]) + (lred[2] + lred[3]);
    atomicAdd(loss, t * (1.25f / 8388608.f));
  }
}

extern "C" void kernel_launch(void* const* d_in, const int* in_sizes, int n_in,
                              void* d_out, int out_size, void* d_ws, size_t ws_size,
                              hipStream_t stream) {
  const float* x  = (const float*)d_in[0];   // (32,64,64,64) fp32
  const float* cb = (const float*)d_in[1];   // (512,64) fp32
  float* st   = (float*)d_out;               // (32,64,64,64)
  float* idxo = (float*)d_out + ST_ELEMS;    // (32,64,64) as float
  float* loss = (float*)d_out + LOSS_OFF;    // scalar

  hipMemsetAsync(loss, 0, sizeof(float), stream);  // d_out is poisoned each call
  vq_kernel<<<dim3(512), dim3(256), 0, stream>>>(x, cb, st, idxo, loss);
}